// Round 13
// baseline (4055.495 us; speedup 1.0000x reference)
//
#include <hip/hip_runtime.h>
#include <math.h>

typedef __attribute__((ext_vector_type(8))) short bf16x8;
typedef __attribute__((ext_vector_type(4))) float f32x4;
typedef unsigned short u16;

namespace {
constexpr int Bc = 64, Tc = 12, Nn = 1024, Hc = 64, Ec = 10;
constexpr int NB = Nn * Bc;  // 65536
constexpr int Cc = 66;       // unified channel count (enc uses 65, col 65 zeroed)
constexpr int SA = 208;      // XA row stride ([X(66)|Y1(66)|Y2(66)|pad10])
constexpr int KP = 224;      // padded K for gate/update GEMMs (7 x 32)
constexpr int KD = Bc * Ec;  // 640, dec gram K
constexpr int TN = Tc * Nn;  // 12288
// Row index convention: rid = b*Nn + n  (b outer, n inner).
}

#define SWZ(r) (((r) >> 1) & 3)
#define SW8(r) ((r) & 7)

__device__ __forceinline__ void gld16(const void* g, void* l) {
  __builtin_amdgcn_global_load_lds(
      (const __attribute__((address_space(1))) void*)g,
      (__attribute__((address_space(3))) void*)l, 16, 0, 0);
}

__device__ __forceinline__ void split_bf(float v, u16& h, u16& l) {
  unsigned u = __float_as_uint(v);
  unsigned hu = (u + 0x7FFFu + ((u >> 16) & 1u)) & 0xFFFF0000u;
  h = (u16)(hu >> 16);
  float r = v - __uint_as_float(hu);
  unsigned u2 = __float_as_uint(r);
  l = (u16)((u2 + 0x7FFFu + ((u2 >> 16) & 1u)) >> 16);
}
__device__ __forceinline__ u16 bf_rne(float v) {
  unsigned u = __float_as_uint(v);
  return (u16)((u + 0x7FFFu + ((u >> 16) & 1u)) >> 16);
}
__device__ __forceinline__ float bf_to_f(u16 v) {
  return __uint_as_float(((unsigned)v) << 16);
}
__device__ __forceinline__ bf16x8 ldfrag(const u16* p) { return *(const bf16x8*)p; }

// ---------- enc gram: G = emb @ emb^T (Kd small, fp32) ----------
__global__ __launch_bounds__(256) void k_gram(const float* __restrict__ in, int Kd,
                                              float* __restrict__ G) {
  __shared__ float At[16][64];
  __shared__ float Bt[16][64];
  int i0 = blockIdx.y * 64, j0 = blockIdx.x * 64;
  int tx = threadIdx.x & 15, ty = threadIdx.x >> 4;
  float acc[4][4] = {};
  for (int k0 = 0; k0 < Kd; k0 += 16) {
    for (int u = threadIdx.x; u < 1024; u += 256) {
      int i = u >> 4, k = u & 15;
      At[k][i] = (k0 + k < Kd) ? in[(size_t)(i0 + i) * Kd + k0 + k] : 0.f;
    }
    for (int u = threadIdx.x; u < 1024; u += 256) {
      int j = u >> 4, k = u & 15;
      Bt[k][j] = (k0 + k < Kd) ? in[(size_t)(j0 + j) * Kd + k0 + k] : 0.f;
    }
    __syncthreads();
#pragma unroll
    for (int kk = 0; kk < 16; kk++) {
      float a[4], b[4];
#pragma unroll
      for (int p = 0; p < 4; p++) a[p] = At[kk][ty * 4 + p];
#pragma unroll
      for (int q = 0; q < 4; q++) b[q] = Bt[kk][tx * 4 + q];
#pragma unroll
      for (int p = 0; p < 4; p++)
#pragma unroll
        for (int q = 0; q < 4; q++) acc[p][q] = fmaf(a[p], b[q], acc[p][q]);
    }
    __syncthreads();
  }
  for (int p = 0; p < 4; p++)
    for (int q = 0; q < 4; q++)
      G[(size_t)(i0 + ty * 4 + p) * Nn + j0 + tx * 4 + q] = acc[p][q];
}

// ---------- dec gram via split-MFMA: G = DE @ DE^T ----------
__global__ __launch_bounds__(256) void k_gram_mfma(const u16* __restrict__ Dh,
                                                   const u16* __restrict__ Dl,
                                                   float* __restrict__ G) {
  __shared__ u16 lds[12288];
  const int tid = threadIdx.x;
  const int wave = tid >> 6, lane = tid & 63;
  const int i0 = blockIdx.y * 64;
  const int j0 = blockIdx.x * 128;
  const int wy = wave >> 1, wx = wave & 1;
  const int m = lane & 15, quad = lane >> 4;

  f32x4 acc[2][4];
  f32x4 z4 = {0.f, 0.f, 0.f, 0.f};
#pragma unroll
  for (int a = 0; a < 2; a++)
#pragma unroll
    for (int q = 0; q < 4; q++) acc[a][q] = z4;

  const int ar = tid >> 2;
  const int akc = (tid & 3) ^ SWZ(ar);

  for (int k0 = 0; k0 < KD; k0 += 32) {
    gld16(Dh + (size_t)(i0 + ar) * KD + k0 + akc * 8, &lds[wave * 512]);
    gld16(Dl + (size_t)(i0 + ar) * KD + k0 + akc * 8, &lds[2048 + wave * 512]);
#pragma unroll
    for (int p = 0; p < 2; p++) {
      int r = p * 64 + (tid >> 2);
      int kc = (tid & 3) ^ SWZ(r);
      gld16(Dh + (size_t)(j0 + r) * KD + k0 + kc * 8, &lds[4096 + p * 2048 + wave * 512]);
      gld16(Dl + (size_t)(j0 + r) * KD + k0 + kc * 8, &lds[8192 + p * 2048 + wave * 512]);
    }
    __syncthreads();

    bf16x8 ah[2], al[2], bh[4], bl[4];
#pragma unroll
    for (int mb = 0; mb < 2; mb++) {
      int r = wy * 32 + mb * 16 + m;
      int ci = r * 4 + (quad ^ SWZ(r));
      ah[mb] = *(const bf16x8*)&lds[ci * 8];
      al[mb] = *(const bf16x8*)&lds[2048 + ci * 8];
    }
#pragma unroll
    for (int nb = 0; nb < 4; nb++) {
      int rj = wx * 64 + nb * 16 + m;
      int cj = rj * 4 + (quad ^ SWZ(rj));
      bh[nb] = *(const bf16x8*)&lds[4096 + cj * 8];
      bl[nb] = *(const bf16x8*)&lds[8192 + cj * 8];
    }
#pragma unroll
    for (int mb = 0; mb < 2; mb++)
#pragma unroll
      for (int nb = 0; nb < 4; nb++) {
        acc[mb][nb] = __builtin_amdgcn_mfma_f32_16x16x32_bf16(ah[mb], bh[nb], acc[mb][nb], 0, 0, 0);
        acc[mb][nb] = __builtin_amdgcn_mfma_f32_16x16x32_bf16(ah[mb], bl[nb], acc[mb][nb], 0, 0, 0);
        acc[mb][nb] = __builtin_amdgcn_mfma_f32_16x16x32_bf16(al[mb], bh[nb], acc[mb][nb], 0, 0, 0);
      }
    __syncthreads();
  }

#pragma unroll
  for (int mb = 0; mb < 2; mb++)
#pragma unroll
    for (int nb = 0; nb < 4; nb++) {
      int col = j0 + wx * 64 + nb * 16 + m;
#pragma unroll
      for (int p = 0; p < 4; p++) {
        int row = i0 + wy * 32 + mb * 16 + quad * 4 + p;
        G[(size_t)row * Nn + col] = acc[mb][nb][p];
      }
    }
}

// ---------- S = row_softmax(relu(G)) -> split to S1h/S1l ----------
__global__ __launch_bounds__(256) void k_softmax(const float* __restrict__ G,
                                                 u16* __restrict__ S1h,
                                                 u16* __restrict__ S1l) {
  __shared__ float sred[8];
  int n = blockIdx.x;
  float v[4];
#pragma unroll
  for (int i = 0; i < 4; i++)
    v[i] = fmaxf(G[(size_t)n * Nn + threadIdx.x + i * 256], 0.f);
  float mx = fmaxf(fmaxf(v[0], v[1]), fmaxf(v[2], v[3]));
  for (int off = 32; off > 0; off >>= 1) mx = fmaxf(mx, __shfl_down(mx, off));
  if ((threadIdx.x & 63) == 0) sred[threadIdx.x >> 6] = mx;
  __syncthreads();
  float rmax = fmaxf(fmaxf(sred[0], sred[1]), fmaxf(sred[2], sred[3]));
  float s = 0.f;
#pragma unroll
  for (int i = 0; i < 4; i++) { v[i] = expf(v[i] - rmax); s += v[i]; }
  for (int off = 32; off > 0; off >>= 1) s += __shfl_down(s, off);
  if ((threadIdx.x & 63) == 0) sred[4 + (threadIdx.x >> 6)] = s;
  __syncthreads();
  float inv = 1.f / (sred[4] + sred[5] + sred[6] + sred[7]);
#pragma unroll
  for (int i = 0; i < 4; i++) {
    u16 h, l;
    split_bf(v[i] * inv, h, l);
    size_t a = (size_t)n * Nn + threadIdx.x + i * 256;
    S1h[a] = h; S1l[a] = l;
  }
}

// ---------- transpose S1h/S1l -> Sth/Stl ----------
__global__ __launch_bounds__(256) void k_tr2(const u16* __restrict__ Ah,
                                             const u16* __restrict__ Al,
                                             u16* __restrict__ Th, u16* __restrict__ Tl) {
  __shared__ u16 sm[64][72];
  int i0 = blockIdx.y * 64, j0 = blockIdx.x * 64;
  int tid = threadIdx.x;
  for (int pass = 0; pass < 2; pass++) {
    const u16* src = pass ? Al : Ah;
    u16* dst = pass ? Tl : Th;
    for (int u = tid; u < 4096; u += 256) {
      int i = u >> 6, c = u & 63;
      sm[i][c] = src[(size_t)(i0 + i) * Nn + j0 + c];
    }
    __syncthreads();
    for (int u = tid; u < 4096; u += 256) {
      int c = u >> 6, i = u & 63;
      dst[(size_t)(j0 + c) * Nn + i0 + i] = sm[i][c];
    }
    __syncthreads();
  }
}

// ---------- S2 = 2*S@S - I via direct-fragment split MFMA (3-term, bf16 out) ----------
// BM=64, BN=64, grid 256 (1 block/CU): i0 = (blk&15)*64, j0 = (blk>>4)*64.
__global__ __launch_bounds__(256) void k_s2_mfma(const u16* __restrict__ S1h,
                                                 const u16* __restrict__ S1l,
                                                 const u16* __restrict__ Sth,
                                                 const u16* __restrict__ Stl,
                                                 u16* __restrict__ S2h) {
  const int tid = threadIdx.x;
  const int wave = tid >> 6, lane = tid & 63;
  const int blk = blockIdx.x;
  const int i0 = (blk & 15) * 64;
  const int j0 = (blk >> 4) * 64;
  const int wy = wave >> 1, wx = wave & 1;
  const int m = lane & 15, quad = lane >> 4;

  const size_t aoff = (size_t)(i0 + wy * 32 + m) * Nn + quad * 8;
  const size_t boff = (size_t)(j0 + wx * 32 + m) * Nn + quad * 8;

  f32x4 acc[2][2];
  f32x4 z4 = {0.f, 0.f, 0.f, 0.f};
#pragma unroll
  for (int a = 0; a < 2; a++) { acc[a][0] = z4; acc[a][1] = z4; }

  bf16x8 fAh[2][2], fAl[2][2], fBh[2][2], fBl[2][2];
  auto ld = [&](int k0, int sb) {
#pragma unroll
    for (int mb = 0; mb < 2; mb++) {
      fAh[sb][mb] = ldfrag(S1h + aoff + (size_t)mb * 16 * Nn + k0);
      fAl[sb][mb] = ldfrag(S1l + aoff + (size_t)mb * 16 * Nn + k0);
    }
#pragma unroll
    for (int nb = 0; nb < 2; nb++) {
      fBh[sb][nb] = ldfrag(Sth + boff + (size_t)nb * 16 * Nn + k0);
      fBl[sb][nb] = ldfrag(Stl + boff + (size_t)nb * 16 * Nn + k0);
    }
  };
  ld(0, 0);
#pragma unroll 2
  for (int kt = 0; kt < 32; kt++) {
    int cur = kt & 1;
    if (kt < 31) ld((kt + 1) * 32, cur ^ 1);
#pragma unroll
    for (int mb = 0; mb < 2; mb++)
#pragma unroll
      for (int nb = 0; nb < 2; nb++) {
        acc[mb][nb] = __builtin_amdgcn_mfma_f32_16x16x32_bf16(fAh[cur][mb], fBh[cur][nb], acc[mb][nb], 0, 0, 0);
        acc[mb][nb] = __builtin_amdgcn_mfma_f32_16x16x32_bf16(fAh[cur][mb], fBl[cur][nb], acc[mb][nb], 0, 0, 0);
        acc[mb][nb] = __builtin_amdgcn_mfma_f32_16x16x32_bf16(fAl[cur][mb], fBh[cur][nb], acc[mb][nb], 0, 0, 0);
      }
  }

#pragma unroll
  for (int mb = 0; mb < 2; mb++)
#pragma unroll
    for (int nb = 0; nb < 2; nb++) {
      int col = j0 + wx * 32 + nb * 16 + m;
#pragma unroll
      for (int p = 0; p < 4; p++) {
        int row = i0 + wy * 32 + mb * 16 + quad * 4 + p;
        float v = 2.f * acc[mb][nb][p] - (row == col ? 1.f : 0.f);
        S2h[(size_t)row * Nn + col] = bf_rne(v);
      }
    }
}

// ---------- Wt prep (split hi/lo) ----------
__global__ __launch_bounds__(256) void k_prep_wt(const float* __restrict__ W, int Csrc,
                                                 int ncol, u16* __restrict__ Wh,
                                                 u16* __restrict__ Wl) {
  int idx = blockIdx.x * 256 + threadIdx.x;
  if (idx >= ncol * KP) return;
  int n = idx / KP, kp = idx % KP;
  int chunk = kp / Cc, c = kp % Cc;
  float v = 0.f;
  if (kp < 3 * Cc && c < Csrc) v = W[((size_t)chunk * Csrc + c) * ncol + n];
  u16 h, l;
  split_bf(v, h, l);
  Wh[idx] = h; Wl[idx] = l;
}

// ---------- fill enc: rid = b*Nn + n ----------
__global__ __launch_bounds__(256) void k_fill_enc(const float* __restrict__ x,
                                                  u16* __restrict__ XAh,
                                                  u16* __restrict__ Xth, int t) {
  int idx = blockIdx.x * 256 + threadIdx.x;
  if (idx >= NB) return;
  int n = idx & (Nn - 1), b = idx >> 10;
  u16 h = bf_rne(x[(size_t)b * TN + t * Nn + n]);
  XAh[(size_t)idx * SA] = h;
  Xth[(size_t)b * Cc * Nn + n] = h;
}

// ---------- dec init ----------
__global__ __launch_bounds__(256) void k_dec_init(const float* __restrict__ x,
                                                  const float* __restrict__ ycov,
                                                  u16* __restrict__ XAh,
                                                  u16* __restrict__ Xth) {
  int idx = blockIdx.x * 256 + threadIdx.x;
  if (idx >= NB) return;
  int n = idx & (Nn - 1), b = idx >> 10;
  u16 h0 = bf_rne(x[(size_t)b * TN + (size_t)(Tc - 1) * Nn + n]);
  u16 h1 = bf_rne(ycov[(size_t)b * TN + n]);
  XAh[(size_t)idx * SA] = h0;
  XAh[(size_t)idx * SA + 1] = h1;
  Xth[((size_t)b * Cc) * Nn + n] = h0;
  Xth[((size_t)b * Cc + 1) * Nn + n] = h1;
}

// ---------- ygemm: Y1 = S1@X, Y2 = S2@X. BK=64, single 48KB buffer, XCD i0-cluster ----------
__global__ __launch_bounds__(256, 2) void k_ygemm(const u16* __restrict__ S1h,
                                                  const u16* __restrict__ S2h,
                                                  const u16* __restrict__ Xth,
                                                  u16* __restrict__ XA) {
  __shared__ u16 lds[24576];  // 48KB
  const int tid = threadIdx.x;
  const int wave = tid >> 6;
  const int lane = tid & 63;
  const int blk = blockIdx.x;
  const int i0 = (blk & 7) * 128;
  const int j0 = (blk >> 3) * 128;
  const int wy = wave >> 1, wx = wave & 1;
  const int m = lane & 15, quad = lane >> 4;

  f32x4 acc1[4][4], acc2[4][4];
  f32x4 z4 = {0.f, 0.f, 0.f, 0.f};
#pragma unroll
  for (int a = 0; a < 4; a++)
#pragma unroll
    for (int q = 0; q < 4; q++) { acc1[a][q] = z4; acc2[a][q] = z4; }

  for (int k0 = 0; k0 < Nn; k0 += 64) {
#pragma unroll
    for (int c = 0; c < 4; c++) {
      int ci = c * 256 + tid;
      int r = ci >> 3, kc = (ci & 7) ^ SW8(r);
      gld16(S1h + (size_t)(i0 + r) * Nn + k0 + kc * 8, &lds[c * 2048 + wave * 512]);
      gld16(S2h + (size_t)(i0 + r) * Nn + k0 + kc * 8, &lds[8192 + c * 2048 + wave * 512]);
      gld16(Xth + (size_t)(j0 + r) * Nn + k0 + kc * 8, &lds[16384 + c * 2048 + wave * 512]);
    }
    __syncthreads();

#pragma unroll
    for (int ks = 0; ks < 2; ks++) {
      bf16x8 bfr[4];
#pragma unroll
      for (int nb = 0; nb < 4; nb++) {
        int rj = wx * 64 + nb * 16 + m;
        int cj = rj * 8 + ((ks * 4 + quad) ^ SW8(rj));
        bfr[nb] = *(const bf16x8*)&lds[16384 + cj * 8];
      }
      bf16x8 a1[4], a2[4];
#pragma unroll
      for (int mb = 0; mb < 4; mb++) {
        int r = wy * 64 + mb * 16 + m;
        int ci = r * 8 + ((ks * 4 + quad) ^ SW8(r));
        a1[mb] = *(const bf16x8*)&lds[ci * 8];
        a2[mb] = *(const bf16x8*)&lds[8192 + ci * 8];
      }
#pragma unroll
      for (int mb = 0; mb < 4; mb++)
#pragma unroll
        for (int nb = 0; nb < 4; nb++) {
          acc1[mb][nb] = __builtin_amdgcn_mfma_f32_16x16x32_bf16(a1[mb], bfr[nb], acc1[mb][nb], 0, 0, 0);
          acc2[mb][nb] = __builtin_amdgcn_mfma_f32_16x16x32_bf16(a2[mb], bfr[nb], acc2[mb][nb], 0, 0, 0);
        }
    }
    __syncthreads();
  }

#pragma unroll
  for (int mb = 0; mb < 4; mb++)
#pragma unroll
    for (int nb = 0; nb < 4; nb++) {
      int col = j0 + wx * 64 + nb * 16 + m;
      int bb = col / Cc, cc = col % Cc;
#pragma unroll
      for (int p = 0; p < 4; p++) {
        int n = i0 + wy * 64 + mb * 16 + quad * 4 + p;
        size_t base = ((size_t)bb * Nn + n) * SA;
        XA[base + 66 + cc] = bf_rne(acc1[mb][nb][p]);
        XA[base + 132 + cc] = bf_rne(acc2[mb][nb][p]);
      }
    }
}

// ---------- gate: sigmoid(XA@W^T+b). BM=256, BN=128, grid 256 ----------
__global__ __launch_bounds__(256) void k_gate(const u16* __restrict__ XA,
                                              const u16* __restrict__ Wh, const u16* __restrict__ Wl,
                                              const float* __restrict__ bias,
                                              const float* __restrict__ hst,
                                              u16* __restrict__ Rb,
                                              u16* __restrict__ XAo,
                                              u16* __restrict__ Xth, int off) {
  __shared__ u16 lds[16384];  // A 8192 | Wh 4096 | Wl 4096 (u16) = 32KB
  const int tid = threadIdx.x;
  const int wave = tid >> 6, lane = tid & 63;
  const int r0 = blockIdx.x * 256;
  const int wy = wave >> 1, wx = wave & 1;
  const int m = lane & 15, quad = lane >> 4;

  f32x4 acc[8][4];
  f32x4 z4 = {0.f, 0.f, 0.f, 0.f};
#pragma unroll
  for (int a = 0; a < 8; a++)
#pragma unroll
    for (int q = 0; q < 4; q++) acc[a][q] = z4;

  for (int kt = 0; kt < 7; kt++) {
    int k0 = kt * 32;
#pragma unroll
    for (int c = 0; c < 4; c++) {
      int ci = c * 256 + tid;
      int r = ci >> 2, kc = (ci & 3) ^ SWZ(r);
      gld16(XA + (size_t)(r0 + r) * SA + k0 + kc * 8, &lds[c * 2048 + wave * 512]);
    }
#pragma unroll
    for (int c = 0; c < 2; c++) {
      int ci = c * 256 + tid;
      int r = ci >> 2, kc = (ci & 3) ^ SWZ(r);
      gld16(Wh + (size_t)r * KP + k0 + kc * 8, &lds[8192 + c * 2048 + wave * 512]);
      gld16(Wl + (size_t)r * KP + k0 + kc * 8, &lds[12288 + c * 2048 + wave * 512]);
    }
    __syncthreads();

    bf16x8 af[8], bh[4], bl[4];
#pragma unroll
    for (int mb = 0; mb < 8; mb++) {
      int r = wy * 128 + mb * 16 + m;
      int ci = r * 4 + (quad ^ SWZ(r));
      af[mb] = *(const bf16x8*)&lds[ci * 8];
    }
#pragma unroll
    for (int nb = 0; nb < 4; nb++) {
      int rj = wx * 64 + nb * 16 + m;
      int cj = rj * 4 + (quad ^ SWZ(rj));
      bh[nb] = *(const bf16x8*)&lds[8192 + cj * 8];
      bl[nb] = *(const bf16x8*)&lds[12288 + cj * 8];
    }
#pragma unroll
    for (int mb = 0; mb < 8; mb++)
#pragma unroll
      for (int nb = 0; nb < 4; nb++) {
        acc[mb][nb] = __builtin_amdgcn_mfma_f32_16x16x32_bf16(af[mb], bh[nb], acc[mb][nb], 0, 0, 0);
        acc[mb][nb] = __builtin_amdgcn_mfma_f32_16x16x32_bf16(af[mb], bl[nb], acc[mb][nb], 0, 0, 0);
      }
    __syncthreads();
  }

#pragma unroll
  for (int mb = 0; mb < 8; mb++)
#pragma unroll
    for (int nb = 0; nb < 4; nb++) {
      int col = wx * 64 + nb * 16 + m;
      float bv = bias[col];
#pragma unroll
      for (int p = 0; p < 4; p++) {
        int rid = r0 + wy * 128 + mb * 16 + quad * 4 + p;
        float sg = 1.f / (1.f + expf(-(acc[mb][nb][p] + bv)));
        if (col < 64) {
          float v = sg * hst[(size_t)rid * 64 + col];
          u16 vh = bf_rne(v);
          XAo[(size_t)rid * SA + off + col] = vh;
          int n = rid & (Nn - 1), b = rid >> 10;
          Xth[((size_t)b * Cc + off + col) * Nn + n] = vh;
        } else {
          Rb[(size_t)rid * 64 + col - 64] = bf_rne(sg);
        }
      }
    }
}

// ---------- update: BM=256, BN=64, grid 256; optional enc-fill of x[tnext] ----------
__global__ __launch_bounds__(256) void k_upd(const u16* __restrict__ XA,
                                             const u16* __restrict__ Wh, const u16* __restrict__ Wl,
                                             const float* __restrict__ bias,
                                             const u16* __restrict__ Rb,
                                             float* __restrict__ h,
                                             u16* __restrict__ XAo,
                                             u16* __restrict__ Xth,
                                             const float* __restrict__ xsrc, int tnext,
                                             int off_next) {
  __shared__ u16 lds[12288];  // A 8192 | Wh 2048 | Wl 2048 (u16) = 24KB
  const int tid = threadIdx.x;
  const int wave = tid >> 6, lane = tid & 63;
  const int r0 = blockIdx.x * 256;
  const int wy = wave >> 1, wx = wave & 1;
  const int m = lane & 15, quad = lane >> 4;

  f32x4 acc[8][2];
  f32x4 z4 = {0.f, 0.f, 0.f, 0.f};
#pragma unroll
  for (int a = 0; a < 8; a++) { acc[a][0] = z4; acc[a][1] = z4; }

  for (int kt = 0; kt < 7; kt++) {
    int k0 = kt * 32;
#pragma unroll
    for (int c = 0; c < 4; c++) {
      int ci = c * 256 + tid;
      int r = ci >> 2, kc = (ci & 3) ^ SWZ(r);
      gld16(XA + (size_t)(r0 + r) * SA + k0 + kc * 8, &lds[c * 2048 + wave * 512]);
    }
    {
      int ci = tid;
      int r = ci >> 2, kc = (ci & 3) ^ SWZ(r);
      gld16(Wh + (size_t)r * KP + k0 + kc * 8, &lds[8192 + wave * 512]);
      gld16(Wl + (size_t)r * KP + k0 + kc * 8, &lds[10240 + wave * 512]);
    }
    __syncthreads();

    bf16x8 af[8], bh[2], bl[2];
#pragma unroll
    for (int mb = 0; mb < 8; mb++) {
      int r = wy * 128 + mb * 16 + m;
      int ci = r * 4 + (quad ^ SWZ(r));
      af[mb] = *(const bf16x8*)&lds[ci * 8];
    }
#pragma unroll
    for (int nb = 0; nb < 2; nb++) {
      int rj = wx * 32 + nb * 16 + m;
      int cj = rj * 4 + (quad ^ SWZ(rj));
      bh[nb] = *(const bf16x8*)&lds[8192 + cj * 8];
      bl[nb] = *(const bf16x8*)&lds[10240 + cj * 8];
    }
#pragma unroll
    for (int mb = 0; mb < 8; mb++)
#pragma unroll
      for (int nb = 0; nb < 2; nb++) {
        acc[mb][nb] = __builtin_amdgcn_mfma_f32_16x16x32_bf16(af[mb], bh[nb], acc[mb][nb], 0, 0, 0);
        acc[mb][nb] = __builtin_amdgcn_mfma_f32_16x16x32_bf16(af[mb], bl[nb], acc[mb][nb], 0, 0, 0);
      }
    __syncthreads();
  }

#pragma unroll
  for (int mb = 0; mb < 8; mb++)
#pragma unroll
    for (int nb = 0; nb < 2; nb++) {
      int col = wx * 32 + nb * 16 + m;
      float bv = bias[col];
#pragma unroll
      for (int p = 0; p < 4; p++) {
        int rid = r0 + wy * 128 + mb * 16 + quad * 4 + p;
        float hc = tanhf(acc[mb][nb][p] + bv);
        size_t idx = (size_t)rid * 64 + col;
        float rr = bf_to_f(Rb[idx]);
        float hn = rr * h[idx] + (1.f - rr) * hc;
        h[idx] = hn;
        u16 vh = bf_rne(hn);
        XAo[(size_t)rid * SA + off_next + col] = vh;
        int n = rid & (Nn - 1), b = rid >> 10;
        Xth[((size_t)b * Cc + off_next + col) * Nn + n] = vh;
        if (col == 0 && xsrc != nullptr) {
          u16 xv = bf_rne(xsrc[(size_t)b * TN + (size_t)tnext * Nn + n]);
          XAo[(size_t)rid * SA] = xv;
          Xth[((size_t)b * Cc) * Nn + n] = xv;
        }
      }
    }
}

// ---------- de = h @ FC_E, split output ----------
__global__ __launch_bounds__(256) void k_de(const float* __restrict__ h,
                                            const float* __restrict__ fc,
                                            u16* __restrict__ Dh, u16* __restrict__ Dl) {
  __shared__ float fcs[Hc * Ec];
  for (int j = threadIdx.x; j < Hc * Ec; j += 256) fcs[j] = fc[j];
  __syncthreads();
  int idx = blockIdx.x * 256 + threadIdx.x;
  if (idx >= Nn * KD) return;
  int n = idx / KD;
  int rem = idx % KD;
  int b = rem / Ec, e = rem % Ec;
  const float* hp = h + ((size_t)b * Nn + n) * Hc;
  float acc = 0.f;
#pragma unroll 8
  for (int hh = 0; hh < Hc; hh++) acc = fmaf(hp[hh], fcs[hh * Ec + e], acc);
  u16 vh, vl;
  split_bf(acc, vh, vl);
  Dh[idx] = vh; Dl[idx] = vl;
}

// ---------- proj + fill next dec step ----------
__global__ __launch_bounds__(256) void k_proj_fill(const float* __restrict__ h,
                                                   const float* __restrict__ pw,
                                                   const float* __restrict__ pb,
                                                   const float* __restrict__ ycov,
                                                   u16* __restrict__ XAh,
                                                   u16* __restrict__ Xth,
                                                   float* __restrict__ out, int t) {
  int idx = blockIdx.x * 256 + threadIdx.x;
  if (idx >= NB) return;
  int n = idx & (Nn - 1), b = idx >> 10;
  const float* hp = h + (size_t)idx * Hc;
  float acc = pb[0];
#pragma unroll 8
  for (int i = 0; i < Hc; i++) acc = fmaf(hp[i], pw[i], acc);
  out[(size_t)b * TN + (size_t)t * Nn + n] = acc;
  if (t + 1 < Tc) {
    u16 h0 = bf_rne(acc);
    u16 h1 = bf_rne(ycov[(size_t)b * TN + (size_t)(t + 1) * Nn + n]);
    XAh[(size_t)idx * SA] = h0;
    XAh[(size_t)idx * SA + 1] = h1;
    Xth[((size_t)b * Cc) * Nn + n] = h0;
    Xth[((size_t)b * Cc + 1) * Nn + n] = h1;
  }
}

extern "C" void kernel_launch(void* const* d_in, const int* in_sizes, int n_in,
                              void* d_out, int out_size, void* d_ws, size_t ws_size,
                              hipStream_t stream) {
  (void)in_sizes; (void)n_in; (void)out_size; (void)ws_size;
  const float* x    = (const float*)d_in[0];
  const float* ycov = (const float*)d_in[1];
  const float* emb  = (const float*)d_in[2];
  const float* fce  = (const float*)d_in[3];
  const float* egw  = (const float*)d_in[4];
  const float* egb  = (const float*)d_in[5];
  const float* euw  = (const float*)d_in[6];
  const float* eub  = (const float*)d_in[7];
  const float* dgw  = (const float*)d_in[8];
  const float* dgb  = (const float*)d_in[9];
  const float* duw  = (const float*)d_in[10];
  const float* dub  = (const float*)d_in[11];
  const float* pw   = (const float*)d_in[12];
  const float* pb   = (const float*)d_in[13];
  float* out = (float*)d_out;

  char* wsb = (char*)d_ws;
  size_t off = 0;
  auto alloc = [&](size_t bytes) {
    void* p = wsb + off;
    off = (off + bytes + 255) & ~(size_t)255;
    return p;
  };
  float* Gf = (float*)alloc((size_t)Nn * Nn * 4);
  u16* S1h = (u16*)alloc((size_t)Nn * Nn * 2);
  u16* S1l = (u16*)alloc((size_t)Nn * Nn * 2);
  u16* S2h = (u16*)alloc((size_t)Nn * Nn * 2);
  u16* Sth = (u16*)alloc((size_t)Nn * Nn * 2);
  u16* Stl = (u16*)alloc((size_t)Nn * Nn * 2);
  float* Hst = (float*)alloc((size_t)NB * Hc * 4);
  u16* XAh = (u16*)alloc((size_t)(NB + 4) * SA * 2);
  u16* Xth = (u16*)alloc((size_t)Bc * Cc * Nn * 2);
  u16* Rb = (u16*)alloc((size_t)NB * Hc * 2);
  u16* DEh = (u16*)alloc((size_t)Nn * KD * 2);
  u16* DEl = (u16*)alloc((size_t)Nn * KD * 2);
  u16* WgeH = (u16*)alloc(128 * KP * 2); u16* WgeL = (u16*)alloc(128 * KP * 2);
  u16* WueH = (u16*)alloc(64 * KP * 2);  u16* WueL = (u16*)alloc(64 * KP * 2);
  u16* WgdH = (u16*)alloc(128 * KP * 2); u16* WgdL = (u16*)alloc(128 * KP * 2);
  u16* WudH = (u16*)alloc(64 * KP * 2);  u16* WudL = (u16*)alloc(64 * KP * 2);

  hipMemsetAsync(Hst, 0, (size_t)NB * Hc * 4, stream);
  hipMemsetAsync(XAh, 0, (size_t)(NB + 4) * SA * 2, stream);
  hipMemsetAsync(Xth, 0, (size_t)Bc * Cc * Nn * 2, stream);

  k_prep_wt<<<(128 * KP + 255) / 256, 256, 0, stream>>>(egw, 65, 128, WgeH, WgeL);
  k_prep_wt<<<(64 * KP + 255) / 256, 256, 0, stream>>>(euw, 65, 64, WueH, WueL);
  k_prep_wt<<<(128 * KP + 255) / 256, 256, 0, stream>>>(dgw, 66, 128, WgdH, WgdL);
  k_prep_wt<<<(64 * KP + 255) / 256, 256, 0, stream>>>(duw, 66, 64, WudH, WudL);

  // encoder supports
  k_gram<<<dim3(16, 16), 256, 0, stream>>>(emb, Ec, Gf);
  k_softmax<<<Nn, 256, 0, stream>>>(Gf, S1h, S1l);
  k_tr2<<<dim3(16, 16), 256, 0, stream>>>(S1h, S1l, Sth, Stl);
  k_s2_mfma<<<256, 256, 0, stream>>>(S1h, S1l, Sth, Stl, S2h);

  const int gNB = NB / 256;

  k_fill_enc<<<gNB, 256, 0, stream>>>(x, XAh, Xth, 0);
  for (int t = 0; t < Tc; t++) {
    k_ygemm<<<264, 256, 0, stream>>>(S1h, S2h, Xth, XAh);
    k_gate<<<256, 256, 0, stream>>>(XAh, WgeH, WgeL, egb, Hst, Rb, XAh, Xth, 1);
    k_ygemm<<<264, 256, 0, stream>>>(S1h, S2h, Xth, XAh);
    k_upd<<<256, 256, 0, stream>>>(XAh, WueH, WueL, eub, Rb, Hst, XAh, Xth,
                                   (t + 1 < Tc) ? x : nullptr, t + 1,
                                   (t == Tc - 1) ? 2 : 1);
  }

  // decoder supports
  k_de<<<(Nn * KD + 255) / 256, 256, 0, stream>>>(Hst, fce, DEh, DEl);
  k_gram_mfma<<<dim3(8, 16), 256, 0, stream>>>(DEh, DEl, Gf);
  k_softmax<<<Nn, 256, 0, stream>>>(Gf, S1h, S1l);
  k_tr2<<<dim3(16, 16), 256, 0, stream>>>(S1h, S1l, Sth, Stl);
  k_s2_mfma<<<256, 256, 0, stream>>>(S1h, S1l, Sth, Stl, S2h);
  k_dec_init<<<gNB, 256, 0, stream>>>(x, ycov, XAh, Xth);

  for (int t = 0; t < Tc; t++) {
    k_ygemm<<<264, 256, 0, stream>>>(S1h, S2h, Xth, XAh);
    k_gate<<<256, 256, 0, stream>>>(XAh, WgdH, WgdL, dgb, Hst, Rb, XAh, Xth, 2);
    k_ygemm<<<264, 256, 0, stream>>>(S1h, S2h, Xth, XAh);
    k_upd<<<256, 256, 0, stream>>>(XAh, WudH, WudL, dub, Rb, Hst, XAh, Xth,
                                   nullptr, 0, 2);
    k_proj_fill<<<gNB, 256, 0, stream>>>(Hst, pw, pb, ycov, XAh, Xth, out, t);
  }
}

// Round 14
// 3333.844 us; speedup vs baseline: 1.2165x; 1.2165x over previous
//
#include <hip/hip_runtime.h>
#include <math.h>

typedef __attribute__((ext_vector_type(8))) short bf16x8;
typedef __attribute__((ext_vector_type(4))) float f32x4;
typedef unsigned short u16;

namespace {
constexpr int Bc = 64, Tc = 12, Nn = 1024, Hc = 64, Ec = 10;
constexpr int NB = Nn * Bc;  // 65536
constexpr int Cc = 66;       // unified channel count (enc uses 65, col 65 zeroed)
constexpr int SA = 208;      // XA row stride ([X(66)|Y1(66)|Y2(66)|pad10])
constexpr int KP = 224;      // padded K for gate/update GEMMs (7 x 32)
constexpr int KD = Bc * Ec;  // 640, dec gram K
constexpr int TN = Tc * Nn;  // 12288
// Row index convention: rid = b*Nn + n  (b outer, n inner).
}

#define SWZ(r) (((r) >> 1) & 3)
#define SW8(r) ((r) & 7)

__device__ __forceinline__ void gld16(const void* g, void* l) {
  __builtin_amdgcn_global_load_lds(
      (const __attribute__((address_space(1))) void*)g,
      (__attribute__((address_space(3))) void*)l, 16, 0, 0);
}

__device__ __forceinline__ void split_bf(float v, u16& h, u16& l) {
  unsigned u = __float_as_uint(v);
  unsigned hu = (u + 0x7FFFu + ((u >> 16) & 1u)) & 0xFFFF0000u;
  h = (u16)(hu >> 16);
  float r = v - __uint_as_float(hu);
  unsigned u2 = __float_as_uint(r);
  l = (u16)((u2 + 0x7FFFu + ((u2 >> 16) & 1u)) >> 16);
}
__device__ __forceinline__ u16 bf_rne(float v) {
  unsigned u = __float_as_uint(v);
  return (u16)((u + 0x7FFFu + ((u >> 16) & 1u)) >> 16);
}
__device__ __forceinline__ float bf_to_f(u16 v) {
  return __uint_as_float(((unsigned)v) << 16);
}
__device__ __forceinline__ bf16x8 ldfrag(const u16* p) { return *(const bf16x8*)p; }

// ---------- enc gram: G = emb @ emb^T (Kd small, fp32) ----------
__global__ __launch_bounds__(256) void k_gram(const float* __restrict__ in, int Kd,
                                              float* __restrict__ G) {
  __shared__ float At[16][64];
  __shared__ float Bt[16][64];
  int i0 = blockIdx.y * 64, j0 = blockIdx.x * 64;
  int tx = threadIdx.x & 15, ty = threadIdx.x >> 4;
  float acc[4][4] = {};
  for (int k0 = 0; k0 < Kd; k0 += 16) {
    for (int u = threadIdx.x; u < 1024; u += 256) {
      int i = u >> 4, k = u & 15;
      At[k][i] = (k0 + k < Kd) ? in[(size_t)(i0 + i) * Kd + k0 + k] : 0.f;
    }
    for (int u = threadIdx.x; u < 1024; u += 256) {
      int j = u >> 4, k = u & 15;
      Bt[k][j] = (k0 + k < Kd) ? in[(size_t)(j0 + j) * Kd + k0 + k] : 0.f;
    }
    __syncthreads();
#pragma unroll
    for (int kk = 0; kk < 16; kk++) {
      float a[4], b[4];
#pragma unroll
      for (int p = 0; p < 4; p++) a[p] = At[kk][ty * 4 + p];
#pragma unroll
      for (int q = 0; q < 4; q++) b[q] = Bt[kk][tx * 4 + q];
#pragma unroll
      for (int p = 0; p < 4; p++)
#pragma unroll
        for (int q = 0; q < 4; q++) acc[p][q] = fmaf(a[p], b[q], acc[p][q]);
    }
    __syncthreads();
  }
  for (int p = 0; p < 4; p++)
    for (int q = 0; q < 4; q++)
      G[(size_t)(i0 + ty * 4 + p) * Nn + j0 + tx * 4 + q] = acc[p][q];
}

// ---------- dec gram via split-MFMA: G = DE @ DE^T ----------
__global__ __launch_bounds__(256) void k_gram_mfma(const u16* __restrict__ Dh,
                                                   const u16* __restrict__ Dl,
                                                   float* __restrict__ G) {
  __shared__ u16 lds[12288];
  const int tid = threadIdx.x;
  const int wave = tid >> 6, lane = tid & 63;
  const int i0 = blockIdx.y * 64;
  const int j0 = blockIdx.x * 128;
  const int wy = wave >> 1, wx = wave & 1;
  const int m = lane & 15, quad = lane >> 4;

  f32x4 acc[2][4];
  f32x4 z4 = {0.f, 0.f, 0.f, 0.f};
#pragma unroll
  for (int a = 0; a < 2; a++)
#pragma unroll
    for (int q = 0; q < 4; q++) acc[a][q] = z4;

  const int ar = tid >> 2;
  const int akc = (tid & 3) ^ SWZ(ar);

  for (int k0 = 0; k0 < KD; k0 += 32) {
    gld16(Dh + (size_t)(i0 + ar) * KD + k0 + akc * 8, &lds[wave * 512]);
    gld16(Dl + (size_t)(i0 + ar) * KD + k0 + akc * 8, &lds[2048 + wave * 512]);
#pragma unroll
    for (int p = 0; p < 2; p++) {
      int r = p * 64 + (tid >> 2);
      int kc = (tid & 3) ^ SWZ(r);
      gld16(Dh + (size_t)(j0 + r) * KD + k0 + kc * 8, &lds[4096 + p * 2048 + wave * 512]);
      gld16(Dl + (size_t)(j0 + r) * KD + k0 + kc * 8, &lds[8192 + p * 2048 + wave * 512]);
    }
    __syncthreads();

    bf16x8 ah[2], al[2], bh[4], bl[4];
#pragma unroll
    for (int mb = 0; mb < 2; mb++) {
      int r = wy * 32 + mb * 16 + m;
      int ci = r * 4 + (quad ^ SWZ(r));
      ah[mb] = *(const bf16x8*)&lds[ci * 8];
      al[mb] = *(const bf16x8*)&lds[2048 + ci * 8];
    }
#pragma unroll
    for (int nb = 0; nb < 4; nb++) {
      int rj = wx * 64 + nb * 16 + m;
      int cj = rj * 4 + (quad ^ SWZ(rj));
      bh[nb] = *(const bf16x8*)&lds[4096 + cj * 8];
      bl[nb] = *(const bf16x8*)&lds[8192 + cj * 8];
    }
#pragma unroll
    for (int mb = 0; mb < 2; mb++)
#pragma unroll
      for (int nb = 0; nb < 4; nb++) {
        acc[mb][nb] = __builtin_amdgcn_mfma_f32_16x16x32_bf16(ah[mb], bh[nb], acc[mb][nb], 0, 0, 0);
        acc[mb][nb] = __builtin_amdgcn_mfma_f32_16x16x32_bf16(ah[mb], bl[nb], acc[mb][nb], 0, 0, 0);
        acc[mb][nb] = __builtin_amdgcn_mfma_f32_16x16x32_bf16(al[mb], bh[nb], acc[mb][nb], 0, 0, 0);
      }
    __syncthreads();
  }

#pragma unroll
  for (int mb = 0; mb < 2; mb++)
#pragma unroll
    for (int nb = 0; nb < 4; nb++) {
      int col = j0 + wx * 64 + nb * 16 + m;
#pragma unroll
      for (int p = 0; p < 4; p++) {
        int row = i0 + wy * 32 + mb * 16 + quad * 4 + p;
        G[(size_t)row * Nn + col] = acc[mb][nb][p];
      }
    }
}

// ---------- S = row_softmax(relu(G)) -> split to S1h/S1l ----------
__global__ __launch_bounds__(256) void k_softmax(const float* __restrict__ G,
                                                 u16* __restrict__ S1h,
                                                 u16* __restrict__ S1l) {
  __shared__ float sred[8];
  int n = blockIdx.x;
  float v[4];
#pragma unroll
  for (int i = 0; i < 4; i++)
    v[i] = fmaxf(G[(size_t)n * Nn + threadIdx.x + i * 256], 0.f);
  float mx = fmaxf(fmaxf(v[0], v[1]), fmaxf(v[2], v[3]));
  for (int off = 32; off > 0; off >>= 1) mx = fmaxf(mx, __shfl_down(mx, off));
  if ((threadIdx.x & 63) == 0) sred[threadIdx.x >> 6] = mx;
  __syncthreads();
  float rmax = fmaxf(fmaxf(sred[0], sred[1]), fmaxf(sred[2], sred[3]));
  float s = 0.f;
#pragma unroll
  for (int i = 0; i < 4; i++) { v[i] = expf(v[i] - rmax); s += v[i]; }
  for (int off = 32; off > 0; off >>= 1) s += __shfl_down(s, off);
  if ((threadIdx.x & 63) == 0) sred[4 + (threadIdx.x >> 6)] = s;
  __syncthreads();
  float inv = 1.f / (sred[4] + sred[5] + sred[6] + sred[7]);
#pragma unroll
  for (int i = 0; i < 4; i++) {
    u16 h, l;
    split_bf(v[i] * inv, h, l);
    size_t a = (size_t)n * Nn + threadIdx.x + i * 256;
    S1h[a] = h; S1l[a] = l;
  }
}

// ---------- transpose S1h/S1l -> Sth/Stl ----------
__global__ __launch_bounds__(256) void k_tr2(const u16* __restrict__ Ah,
                                             const u16* __restrict__ Al,
                                             u16* __restrict__ Th, u16* __restrict__ Tl) {
  __shared__ u16 sm[64][72];
  int i0 = blockIdx.y * 64, j0 = blockIdx.x * 64;
  int tid = threadIdx.x;
  for (int pass = 0; pass < 2; pass++) {
    const u16* src = pass ? Al : Ah;
    u16* dst = pass ? Tl : Th;
    for (int u = tid; u < 4096; u += 256) {
      int i = u >> 6, c = u & 63;
      sm[i][c] = src[(size_t)(i0 + i) * Nn + j0 + c];
    }
    __syncthreads();
    for (int u = tid; u < 4096; u += 256) {
      int c = u >> 6, i = u & 63;
      dst[(size_t)(j0 + c) * Nn + i0 + i] = sm[i][c];
    }
    __syncthreads();
  }
}

// ---------- S2 = 2*S@S - I via direct-fragment split MFMA (3-term, bf16 out) ----------
// BM=64, BN=64, grid 256 (1 block/CU): i0 = (blk&15)*64, j0 = (blk>>4)*64.
__global__ __launch_bounds__(256) void k_s2_mfma(const u16* __restrict__ S1h,
                                                 const u16* __restrict__ S1l,
                                                 const u16* __restrict__ Sth,
                                                 const u16* __restrict__ Stl,
                                                 u16* __restrict__ S2h) {
  const int tid = threadIdx.x;
  const int wave = tid >> 6, lane = tid & 63;
  const int blk = blockIdx.x;
  const int i0 = (blk & 15) * 64;
  const int j0 = (blk >> 4) * 64;
  const int wy = wave >> 1, wx = wave & 1;
  const int m = lane & 15, quad = lane >> 4;

  const size_t aoff = (size_t)(i0 + wy * 32 + m) * Nn + quad * 8;
  const size_t boff = (size_t)(j0 + wx * 32 + m) * Nn + quad * 8;

  f32x4 acc[2][2];
  f32x4 z4 = {0.f, 0.f, 0.f, 0.f};
#pragma unroll
  for (int a = 0; a < 2; a++) { acc[a][0] = z4; acc[a][1] = z4; }

  bf16x8 fAh[2][2], fAl[2][2], fBh[2][2], fBl[2][2];
  auto ld = [&](int k0, int sb) {
#pragma unroll
    for (int mb = 0; mb < 2; mb++) {
      fAh[sb][mb] = ldfrag(S1h + aoff + (size_t)mb * 16 * Nn + k0);
      fAl[sb][mb] = ldfrag(S1l + aoff + (size_t)mb * 16 * Nn + k0);
    }
#pragma unroll
    for (int nb = 0; nb < 2; nb++) {
      fBh[sb][nb] = ldfrag(Sth + boff + (size_t)nb * 16 * Nn + k0);
      fBl[sb][nb] = ldfrag(Stl + boff + (size_t)nb * 16 * Nn + k0);
    }
  };
  ld(0, 0);
#pragma unroll 2
  for (int kt = 0; kt < 32; kt++) {
    int cur = kt & 1;
    if (kt < 31) ld((kt + 1) * 32, cur ^ 1);
#pragma unroll
    for (int mb = 0; mb < 2; mb++)
#pragma unroll
      for (int nb = 0; nb < 2; nb++) {
        acc[mb][nb] = __builtin_amdgcn_mfma_f32_16x16x32_bf16(fAh[cur][mb], fBh[cur][nb], acc[mb][nb], 0, 0, 0);
        acc[mb][nb] = __builtin_amdgcn_mfma_f32_16x16x32_bf16(fAh[cur][mb], fBl[cur][nb], acc[mb][nb], 0, 0, 0);
        acc[mb][nb] = __builtin_amdgcn_mfma_f32_16x16x32_bf16(fAl[cur][mb], fBh[cur][nb], acc[mb][nb], 0, 0, 0);
      }
  }

#pragma unroll
  for (int mb = 0; mb < 2; mb++)
#pragma unroll
    for (int nb = 0; nb < 2; nb++) {
      int col = j0 + wx * 32 + nb * 16 + m;
#pragma unroll
      for (int p = 0; p < 4; p++) {
        int row = i0 + wy * 32 + mb * 16 + quad * 4 + p;
        float v = 2.f * acc[mb][nb][p] - (row == col ? 1.f : 0.f);
        S2h[(size_t)row * Nn + col] = bf_rne(v);
      }
    }
}

// ---------- Wt prep (split hi/lo) ----------
__global__ __launch_bounds__(256) void k_prep_wt(const float* __restrict__ W, int Csrc,
                                                 int ncol, u16* __restrict__ Wh,
                                                 u16* __restrict__ Wl) {
  int idx = blockIdx.x * 256 + threadIdx.x;
  if (idx >= ncol * KP) return;
  int n = idx / KP, kp = idx % KP;
  int chunk = kp / Cc, c = kp % Cc;
  float v = 0.f;
  if (kp < 3 * Cc && c < Csrc) v = W[((size_t)chunk * Csrc + c) * ncol + n];
  u16 h, l;
  split_bf(v, h, l);
  Wh[idx] = h; Wl[idx] = l;
}

// ---------- fill enc: rid = b*Nn + n ----------
__global__ __launch_bounds__(256) void k_fill_enc(const float* __restrict__ x,
                                                  u16* __restrict__ XAh,
                                                  u16* __restrict__ Xth, int t) {
  int idx = blockIdx.x * 256 + threadIdx.x;
  if (idx >= NB) return;
  int n = idx & (Nn - 1), b = idx >> 10;
  u16 h = bf_rne(x[(size_t)b * TN + t * Nn + n]);
  XAh[(size_t)idx * SA] = h;
  Xth[(size_t)b * Cc * Nn + n] = h;
}

// ---------- dec init ----------
__global__ __launch_bounds__(256) void k_dec_init(const float* __restrict__ x,
                                                  const float* __restrict__ ycov,
                                                  u16* __restrict__ XAh,
                                                  u16* __restrict__ Xth) {
  int idx = blockIdx.x * 256 + threadIdx.x;
  if (idx >= NB) return;
  int n = idx & (Nn - 1), b = idx >> 10;
  u16 h0 = bf_rne(x[(size_t)b * TN + (size_t)(Tc - 1) * Nn + n]);
  u16 h1 = bf_rne(ycov[(size_t)b * TN + n]);
  XAh[(size_t)idx * SA] = h0;
  XAh[(size_t)idx * SA + 1] = h1;
  Xth[((size_t)b * Cc) * Nn + n] = h0;
  Xth[((size_t)b * Cc + 1) * Nn + n] = h1;
}

// ---------- ygemm: Y1 = S1@X, Y2 = S2@X. BK=64, single 48KB buffer, XCD i0-cluster ----------
__global__ __launch_bounds__(256, 2) void k_ygemm(const u16* __restrict__ S1h,
                                                  const u16* __restrict__ S2h,
                                                  const u16* __restrict__ Xth,
                                                  u16* __restrict__ XA) {
  __shared__ u16 lds[24576];  // 48KB
  const int tid = threadIdx.x;
  const int wave = tid >> 6;
  const int lane = tid & 63;
  const int blk = blockIdx.x;
  const int i0 = (blk & 7) * 128;
  const int j0 = (blk >> 3) * 128;
  const int wy = wave >> 1, wx = wave & 1;
  const int m = lane & 15, quad = lane >> 4;

  f32x4 acc1[4][4], acc2[4][4];
  f32x4 z4 = {0.f, 0.f, 0.f, 0.f};
#pragma unroll
  for (int a = 0; a < 4; a++)
#pragma unroll
    for (int q = 0; q < 4; q++) { acc1[a][q] = z4; acc2[a][q] = z4; }

  for (int k0 = 0; k0 < Nn; k0 += 64) {
#pragma unroll
    for (int c = 0; c < 4; c++) {
      int ci = c * 256 + tid;
      int r = ci >> 3, kc = (ci & 7) ^ SW8(r);
      gld16(S1h + (size_t)(i0 + r) * Nn + k0 + kc * 8, &lds[c * 2048 + wave * 512]);
      gld16(S2h + (size_t)(i0 + r) * Nn + k0 + kc * 8, &lds[8192 + c * 2048 + wave * 512]);
      gld16(Xth + (size_t)(j0 + r) * Nn + k0 + kc * 8, &lds[16384 + c * 2048 + wave * 512]);
    }
    __syncthreads();

#pragma unroll
    for (int ks = 0; ks < 2; ks++) {
      bf16x8 bfr[4];
#pragma unroll
      for (int nb = 0; nb < 4; nb++) {
        int rj = wx * 64 + nb * 16 + m;
        int cj = rj * 8 + ((ks * 4 + quad) ^ SW8(rj));
        bfr[nb] = *(const bf16x8*)&lds[16384 + cj * 8];
      }
      bf16x8 a1[4], a2[4];
#pragma unroll
      for (int mb = 0; mb < 4; mb++) {
        int r = wy * 64 + mb * 16 + m;
        int ci = r * 8 + ((ks * 4 + quad) ^ SW8(r));
        a1[mb] = *(const bf16x8*)&lds[ci * 8];
        a2[mb] = *(const bf16x8*)&lds[8192 + ci * 8];
      }
#pragma unroll
      for (int mb = 0; mb < 4; mb++)
#pragma unroll
        for (int nb = 0; nb < 4; nb++) {
          acc1[mb][nb] = __builtin_amdgcn_mfma_f32_16x16x32_bf16(a1[mb], bfr[nb], acc1[mb][nb], 0, 0, 0);
          acc2[mb][nb] = __builtin_amdgcn_mfma_f32_16x16x32_bf16(a2[mb], bfr[nb], acc2[mb][nb], 0, 0, 0);
        }
    }
    __syncthreads();
  }

#pragma unroll
  for (int mb = 0; mb < 4; mb++)
#pragma unroll
    for (int nb = 0; nb < 4; nb++) {
      int col = j0 + wx * 64 + nb * 16 + m;
      int bb = col / Cc, cc = col % Cc;
#pragma unroll
      for (int p = 0; p < 4; p++) {
        int n = i0 + wy * 64 + mb * 16 + quad * 4 + p;
        size_t base = ((size_t)bb * Nn + n) * SA;
        XA[base + 66 + cc] = bf_rne(acc1[mb][nb][p]);
        XA[base + 132 + cc] = bf_rne(acc2[mb][nb][p]);
      }
    }
}

// ---------- gate: sigmoid(XA@W^T+b); BM=128, grid 512 (2 blocks/CU) ----------
__global__ __launch_bounds__(256) void k_gate(const u16* __restrict__ XA,
                                              const u16* __restrict__ Wh, const u16* __restrict__ Wl,
                                              const float* __restrict__ bias,
                                              const float* __restrict__ hst,
                                              u16* __restrict__ Rb,
                                              u16* __restrict__ XAo,
                                              u16* __restrict__ Xth, int off) {
  __shared__ u16 lds[12288];  // A 4096 | Wh 4096 | Wl 4096
  const int tid = threadIdx.x;
  const int wave = tid >> 6, lane = tid & 63;
  const int r0 = blockIdx.x * 128;
  const int wy = wave >> 1, wx = wave & 1;
  const int m = lane & 15, quad = lane >> 4;

  f32x4 acc[4][4];
  f32x4 z4 = {0.f, 0.f, 0.f, 0.f};
#pragma unroll
  for (int a = 0; a < 4; a++)
#pragma unroll
    for (int q = 0; q < 4; q++) acc[a][q] = z4;

  for (int kt = 0; kt < 7; kt++) {
    int k0 = kt * 32;
#pragma unroll
    for (int c = 0; c < 2; c++) {
      int ci = c * 256 + tid;
      int r = ci >> 2, kc = (ci & 3) ^ SWZ(r);
      gld16(XA + (size_t)(r0 + r) * SA + k0 + kc * 8, &lds[c * 2048 + wave * 512]);
      gld16(Wh + (size_t)r * KP + k0 + kc * 8, &lds[4096 + c * 2048 + wave * 512]);
      gld16(Wl + (size_t)r * KP + k0 + kc * 8, &lds[8192 + c * 2048 + wave * 512]);
    }
    __syncthreads();

    bf16x8 af[4], bh[4], bl[4];
#pragma unroll
    for (int mb = 0; mb < 4; mb++) {
      int r = wy * 64 + mb * 16 + m;
      int ci = r * 4 + (quad ^ SWZ(r));
      af[mb] = *(const bf16x8*)&lds[ci * 8];
    }
#pragma unroll
    for (int nb = 0; nb < 4; nb++) {
      int rj = wx * 64 + nb * 16 + m;
      int cj = rj * 4 + (quad ^ SWZ(rj));
      bh[nb] = *(const bf16x8*)&lds[4096 + cj * 8];
      bl[nb] = *(const bf16x8*)&lds[8192 + cj * 8];
    }
#pragma unroll
    for (int mb = 0; mb < 4; mb++)
#pragma unroll
      for (int nb = 0; nb < 4; nb++) {
        acc[mb][nb] = __builtin_amdgcn_mfma_f32_16x16x32_bf16(af[mb], bh[nb], acc[mb][nb], 0, 0, 0);
        acc[mb][nb] = __builtin_amdgcn_mfma_f32_16x16x32_bf16(af[mb], bl[nb], acc[mb][nb], 0, 0, 0);
      }
    __syncthreads();
  }

#pragma unroll
  for (int mb = 0; mb < 4; mb++)
#pragma unroll
    for (int nb = 0; nb < 4; nb++) {
      int col = wx * 64 + nb * 16 + m;
      float bv = bias[col];
#pragma unroll
      for (int p = 0; p < 4; p++) {
        int rid = r0 + wy * 64 + mb * 16 + quad * 4 + p;
        float sg = 1.f / (1.f + expf(-(acc[mb][nb][p] + bv)));
        if (col < 64) {
          float v = sg * hst[(size_t)rid * 64 + col];
          u16 vh = bf_rne(v);
          XAo[(size_t)rid * SA + off + col] = vh;
          int n = rid & (Nn - 1), b = rid >> 10;
          Xth[((size_t)b * Cc + off + col) * Nn + n] = vh;
        } else {
          Rb[(size_t)rid * 64 + col - 64] = bf_rne(sg);
        }
      }
    }
}

// ---------- update: BM=128, grid 512; optional enc-fill of x[tnext] ----------
__global__ __launch_bounds__(256) void k_upd(const u16* __restrict__ XA,
                                             const u16* __restrict__ Wh, const u16* __restrict__ Wl,
                                             const float* __restrict__ bias,
                                             const u16* __restrict__ Rb,
                                             float* __restrict__ h,
                                             u16* __restrict__ XAo,
                                             u16* __restrict__ Xth,
                                             const float* __restrict__ xsrc, int tnext,
                                             int off_next) {
  __shared__ u16 lds[8192];  // A 4096 | Wh 2048 | Wl 2048
  const int tid = threadIdx.x;
  const int wave = tid >> 6, lane = tid & 63;
  const int r0 = blockIdx.x * 128;
  const int wy = wave >> 1, wx = wave & 1;
  const int m = lane & 15, quad = lane >> 4;

  f32x4 acc[4][2];
  f32x4 z4 = {0.f, 0.f, 0.f, 0.f};
#pragma unroll
  for (int a = 0; a < 4; a++) { acc[a][0] = z4; acc[a][1] = z4; }

  for (int kt = 0; kt < 7; kt++) {
    int k0 = kt * 32;
#pragma unroll
    for (int c = 0; c < 2; c++) {
      int ci = c * 256 + tid;
      int r = ci >> 2, kc = (ci & 3) ^ SWZ(r);
      gld16(XA + (size_t)(r0 + r) * SA + k0 + kc * 8, &lds[c * 2048 + wave * 512]);
    }
    {
      int ci = tid;
      int r = ci >> 2, kc = (ci & 3) ^ SWZ(r);
      gld16(Wh + (size_t)r * KP + k0 + kc * 8, &lds[4096 + wave * 512]);
      gld16(Wl + (size_t)r * KP + k0 + kc * 8, &lds[6144 + wave * 512]);
    }
    __syncthreads();

    bf16x8 af[4], bh[2], bl[2];
#pragma unroll
    for (int mb = 0; mb < 4; mb++) {
      int r = wy * 64 + mb * 16 + m;
      int ci = r * 4 + (quad ^ SWZ(r));
      af[mb] = *(const bf16x8*)&lds[ci * 8];
    }
#pragma unroll
    for (int nb = 0; nb < 2; nb++) {
      int rj = wx * 32 + nb * 16 + m;
      int cj = rj * 4 + (quad ^ SWZ(rj));
      bh[nb] = *(const bf16x8*)&lds[4096 + cj * 8];
      bl[nb] = *(const bf16x8*)&lds[6144 + cj * 8];
    }
#pragma unroll
    for (int mb = 0; mb < 4; mb++)
#pragma unroll
      for (int nb = 0; nb < 2; nb++) {
        acc[mb][nb] = __builtin_amdgcn_mfma_f32_16x16x32_bf16(af[mb], bh[nb], acc[mb][nb], 0, 0, 0);
        acc[mb][nb] = __builtin_amdgcn_mfma_f32_16x16x32_bf16(af[mb], bl[nb], acc[mb][nb], 0, 0, 0);
      }
    __syncthreads();
  }

#pragma unroll
  for (int mb = 0; mb < 4; mb++)
#pragma unroll
    for (int nb = 0; nb < 2; nb++) {
      int col = wx * 32 + nb * 16 + m;
      float bv = bias[col];
#pragma unroll
      for (int p = 0; p < 4; p++) {
        int rid = r0 + wy * 64 + mb * 16 + quad * 4 + p;
        float hc = tanhf(acc[mb][nb][p] + bv);
        size_t idx = (size_t)rid * 64 + col;
        float rr = bf_to_f(Rb[idx]);
        float hn = rr * h[idx] + (1.f - rr) * hc;
        h[idx] = hn;
        u16 vh = bf_rne(hn);
        XAo[(size_t)rid * SA + off_next + col] = vh;
        int n = rid & (Nn - 1), b = rid >> 10;
        Xth[((size_t)b * Cc + off_next + col) * Nn + n] = vh;
        if (col == 0 && xsrc != nullptr) {
          u16 xv = bf_rne(xsrc[(size_t)b * TN + (size_t)tnext * Nn + n]);
          XAo[(size_t)rid * SA] = xv;
          Xth[((size_t)b * Cc) * Nn + n] = xv;
        }
      }
    }
}

// ---------- de = h @ FC_E, split output ----------
__global__ __launch_bounds__(256) void k_de(const float* __restrict__ h,
                                            const float* __restrict__ fc,
                                            u16* __restrict__ Dh, u16* __restrict__ Dl) {
  __shared__ float fcs[Hc * Ec];
  for (int j = threadIdx.x; j < Hc * Ec; j += 256) fcs[j] = fc[j];
  __syncthreads();
  int idx = blockIdx.x * 256 + threadIdx.x;
  if (idx >= Nn * KD) return;
  int n = idx / KD;
  int rem = idx % KD;
  int b = rem / Ec, e = rem % Ec;
  const float* hp = h + ((size_t)b * Nn + n) * Hc;
  float acc = 0.f;
#pragma unroll 8
  for (int hh = 0; hh < Hc; hh++) acc = fmaf(hp[hh], fcs[hh * Ec + e], acc);
  u16 vh, vl;
  split_bf(acc, vh, vl);
  Dh[idx] = vh; Dl[idx] = vl;
}

// ---------- proj + fill next dec step ----------
__global__ __launch_bounds__(256) void k_proj_fill(const float* __restrict__ h,
                                                   const float* __restrict__ pw,
                                                   const float* __restrict__ pb,
                                                   const float* __restrict__ ycov,
                                                   u16* __restrict__ XAh,
                                                   u16* __restrict__ Xth,
                                                   float* __restrict__ out, int t) {
  int idx = blockIdx.x * 256 + threadIdx.x;
  if (idx >= NB) return;
  int n = idx & (Nn - 1), b = idx >> 10;
  const float* hp = h + (size_t)idx * Hc;
  float acc = pb[0];
#pragma unroll 8
  for (int i = 0; i < Hc; i++) acc = fmaf(hp[i], pw[i], acc);
  out[(size_t)b * TN + (size_t)t * Nn + n] = acc;
  if (t + 1 < Tc) {
    u16 h0 = bf_rne(acc);
    u16 h1 = bf_rne(ycov[(size_t)b * TN + (size_t)(t + 1) * Nn + n]);
    XAh[(size_t)idx * SA] = h0;
    XAh[(size_t)idx * SA + 1] = h1;
    Xth[((size_t)b * Cc) * Nn + n] = h0;
    Xth[((size_t)b * Cc + 1) * Nn + n] = h1;
  }
}

extern "C" void kernel_launch(void* const* d_in, const int* in_sizes, int n_in,
                              void* d_out, int out_size, void* d_ws, size_t ws_size,
                              hipStream_t stream) {
  (void)in_sizes; (void)n_in; (void)out_size; (void)ws_size;
  const float* x    = (const float*)d_in[0];
  const float* ycov = (const float*)d_in[1];
  const float* emb  = (const float*)d_in[2];
  const float* fce  = (const float*)d_in[3];
  const float* egw  = (const float*)d_in[4];
  const float* egb  = (const float*)d_in[5];
  const float* euw  = (const float*)d_in[6];
  const float* eub  = (const float*)d_in[7];
  const float* dgw  = (const float*)d_in[8];
  const float* dgb  = (const float*)d_in[9];
  const float* duw  = (const float*)d_in[10];
  const float* dub  = (const float*)d_in[11];
  const float* pw   = (const float*)d_in[12];
  const float* pb   = (const float*)d_in[13];
  float* out = (float*)d_out;

  char* wsb = (char*)d_ws;
  size_t off = 0;
  auto alloc = [&](size_t bytes) {
    void* p = wsb + off;
    off = (off + bytes + 255) & ~(size_t)255;
    return p;
  };
  float* Gf = (float*)alloc((size_t)Nn * Nn * 4);
  u16* S1h = (u16*)alloc((size_t)Nn * Nn * 2);
  u16* S1l = (u16*)alloc((size_t)Nn * Nn * 2);
  u16* S2h = (u16*)alloc((size_t)Nn * Nn * 2);
  u16* Sth = (u16*)alloc((size_t)Nn * Nn * 2);
  u16* Stl = (u16*)alloc((size_t)Nn * Nn * 2);
  float* Hst = (float*)alloc((size_t)NB * Hc * 4);
  u16* XAh = (u16*)alloc((size_t)(NB + 4) * SA * 2);
  u16* Xth = (u16*)alloc((size_t)Bc * Cc * Nn * 2);
  u16* Rb = (u16*)alloc((size_t)NB * Hc * 2);
  u16* DEh = (u16*)alloc((size_t)Nn * KD * 2);
  u16* DEl = (u16*)alloc((size_t)Nn * KD * 2);
  u16* WgeH = (u16*)alloc(128 * KP * 2); u16* WgeL = (u16*)alloc(128 * KP * 2);
  u16* WueH = (u16*)alloc(64 * KP * 2);  u16* WueL = (u16*)alloc(64 * KP * 2);
  u16* WgdH = (u16*)alloc(128 * KP * 2); u16* WgdL = (u16*)alloc(128 * KP * 2);
  u16* WudH = (u16*)alloc(64 * KP * 2);  u16* WudL = (u16*)alloc(64 * KP * 2);

  hipMemsetAsync(Hst, 0, (size_t)NB * Hc * 4, stream);
  hipMemsetAsync(XAh, 0, (size_t)(NB + 4) * SA * 2, stream);
  hipMemsetAsync(Xth, 0, (size_t)Bc * Cc * Nn * 2, stream);

  k_prep_wt<<<(128 * KP + 255) / 256, 256, 0, stream>>>(egw, 65, 128, WgeH, WgeL);
  k_prep_wt<<<(64 * KP + 255) / 256, 256, 0, stream>>>(euw, 65, 64, WueH, WueL);
  k_prep_wt<<<(128 * KP + 255) / 256, 256, 0, stream>>>(dgw, 66, 128, WgdH, WgdL);
  k_prep_wt<<<(64 * KP + 255) / 256, 256, 0, stream>>>(duw, 66, 64, WudH, WudL);

  // encoder supports
  k_gram<<<dim3(16, 16), 256, 0, stream>>>(emb, Ec, Gf);
  k_softmax<<<Nn, 256, 0, stream>>>(Gf, S1h, S1l);
  k_tr2<<<dim3(16, 16), 256, 0, stream>>>(S1h, S1l, Sth, Stl);
  k_s2_mfma<<<256, 256, 0, stream>>>(S1h, S1l, Sth, Stl, S2h);

  const int gNB = NB / 256;

  k_fill_enc<<<gNB, 256, 0, stream>>>(x, XAh, Xth, 0);
  for (int t = 0; t < Tc; t++) {
    k_ygemm<<<264, 256, 0, stream>>>(S1h, S2h, Xth, XAh);
    k_gate<<<512, 256, 0, stream>>>(XAh, WgeH, WgeL, egb, Hst, Rb, XAh, Xth, 1);
    k_ygemm<<<264, 256, 0, stream>>>(S1h, S2h, Xth, XAh);
    k_upd<<<512, 256, 0, stream>>>(XAh, WueH, WueL, eub, Rb, Hst, XAh, Xth,
                                   (t + 1 < Tc) ? x : nullptr, t + 1,
                                   (t == Tc - 1) ? 2 : 1);
  }

  // decoder supports
  k_de<<<(Nn * KD + 255) / 256, 256, 0, stream>>>(Hst, fce, DEh, DEl);
  k_gram_mfma<<<dim3(8, 16), 256, 0, stream>>>(DEh, DEl, Gf);
  k_softmax<<<Nn, 256, 0, stream>>>(Gf, S1h, S1l);
  k_tr2<<<dim3(16, 16), 256, 0, stream>>>(S1h, S1l, Sth, Stl);
  k_s2_mfma<<<256, 256, 0, stream>>>(S1h, S1l, Sth, Stl, S2h);
  k_dec_init<<<gNB, 256, 0, stream>>>(x, ycov, XAh, Xth);

  for (int t = 0; t < Tc; t++) {
    k_ygemm<<<264, 256, 0, stream>>>(S1h, S2h, Xth, XAh);
    k_gate<<<512, 256, 0, stream>>>(XAh, WgdH, WgdL, dgb, Hst, Rb, XAh, Xth, 2);
    k_ygemm<<<264, 256, 0, stream>>>(S1h, S2h, Xth, XAh);
    k_upd<<<512, 256, 0, stream>>>(XAh, WudH, WudL, dub, Rb, Hst, XAh, Xth,
                                   nullptr, 0, 2);
    k_proj_fill<<<gNB, 256, 0, stream>>>(Hst, pw, pb, ycov, XAh, Xth, out, t);
  }
}